// Round 1
// baseline (862.832 us; speedup 1.0000x reference)
//
#include <hip/hip_runtime.h>
#include <hip/hip_bf16.h>

#define N_NODES 100000
#define N_EDGES 1600000
#define OUTF 128
#define INF 256
#define SCAN_CHUNK 1024
#define SCAN_BLOCKS 98   // 98*1024 = 100352 >= 100000
#define NODE_TILE 16

// ---------------- degree count ----------------
__global__ void count_deg_kernel(const int* __restrict__ dst, int E, int* __restrict__ deg) {
    int i = blockIdx.x * blockDim.x + threadIdx.x;
    if (i < E) atomicAdd(&deg[dst[i]], 1);
}

// ---------------- scan step 1: per-chunk sums ----------------
__global__ __launch_bounds__(256) void scan_partial_kernel(const int* __restrict__ deg, int n,
                                                           int* __restrict__ partial) {
    __shared__ int red[256];
    int b = blockIdx.x, t = threadIdx.x;
    int base = b * SCAN_CHUNK;
    int s = 0;
    for (int i = t; i < SCAN_CHUNK; i += 256) {
        int idx = base + i;
        if (idx < n) s += deg[idx];
    }
    red[t] = s;
    __syncthreads();
    for (int off = 128; off > 0; off >>= 1) {
        if (t < off) red[t] += red[t + off];
        __syncthreads();
    }
    if (t == 0) partial[b] = red[0];
}

// ---------------- scan step 2: exclusive scan of partials (nb <= 128) ----------------
__global__ __launch_bounds__(128) void scan_top_kernel(int* __restrict__ partial, int nb,
                                                       int* __restrict__ row_start, int n) {
    __shared__ int sc[128];
    int t = threadIdx.x;
    int v = (t < nb) ? partial[t] : 0;
    sc[t] = v;
    __syncthreads();
    for (int off = 1; off < 128; off <<= 1) {
        int val = sc[t];
        int add = (t >= off) ? sc[t - off] : 0;
        __syncthreads();
        sc[t] = val + add;
        __syncthreads();
    }
    if (t < nb) partial[t] = sc[t] - v;   // exclusive
    if (t == 127) row_start[n] = sc[127]; // total edge count
}

// ---------------- scan step 3: per-chunk exclusive scan + norms ----------------
__global__ __launch_bounds__(256) void scan_final_kernel(const int* __restrict__ deg, int n,
                                                         const int* __restrict__ partial,
                                                         int* __restrict__ row_start,
                                                         int* __restrict__ cursor,
                                                         float* __restrict__ norm1,
                                                         float* __restrict__ norm2) {
    __shared__ int sc[256];
    int b = blockIdx.x, t = threadIdx.x;
    int base = b * SCAN_CHUNK + t * 4;
    int v[4];
    int tsum = 0;
#pragma unroll
    for (int j = 0; j < 4; j++) {
        int idx = base + j;
        v[j] = (idx < n) ? deg[idx] : 0;
        tsum += v[j];
    }
    sc[t] = tsum;
    __syncthreads();
    // inclusive Hillis-Steele over 256 thread sums
    for (int off = 1; off < 256; off <<= 1) {
        int val = sc[t];
        int add = (t >= off) ? sc[t - off] : 0;
        __syncthreads();
        sc[t] = val + add;
        __syncthreads();
    }
    int run = sc[t] - tsum + partial[b];
#pragma unroll
    for (int j = 0; j < 4; j++) {
        int idx = base + j;
        if (idx < n) {
            row_start[idx] = run;
            cursor[idx] = run;
            float d = (float)(v[j] > 0 ? v[j] : 1); // clip(deg, 1)
            norm1[idx] = rsqrtf(d);
            norm2[idx] = 1.0f / d;
            run += v[j];
        }
    }
}

// ---------------- edge scatter into CSR slots ----------------
__global__ void scatter_edges_kernel(const int* __restrict__ src, const int* __restrict__ dst,
                                     int E, int* __restrict__ cursor, int* __restrict__ srcs_sorted) {
    int i = blockIdx.x * blockDim.x + threadIdx.x;
    if (i < E) {
        int d = dst[i];
        int p = atomicAdd(&cursor[d], 1);
        srcs_sorted[p] = src[i];
    }
}

// ---------------- fused projection + relu + attention + msg scale ----------------
// block = 256 threads, handles NODE_TILE=16 nodes. thread t: col c = t&127, node group g = t>>7
__global__ __launch_bounds__(256) void proj_kernel(const float* __restrict__ feat,
                                                   const float* __restrict__ Wm,
                                                   const float* __restrict__ Wv,
                                                   const float* __restrict__ norm1,
                                                   const float* __restrict__ norm2,
                                                   float* __restrict__ m_msg,
                                                   float* __restrict__ v_msg, int n_nodes) {
    __shared__ float feat_s[NODE_TILE][INF];
    int node0 = blockIdx.x * NODE_TILE;
    int tid = threadIdx.x;
    // cooperative load of 16x256 floats = 1024 float4
    {
        const float4* fsrc = (const float4*)(feat + (size_t)node0 * INF);
        float4* fdst = (float4*)(&feat_s[0][0]);
        int max4 = ((n_nodes - node0 < NODE_TILE ? n_nodes - node0 : NODE_TILE) * INF) >> 2;
#pragma unroll
        for (int i = 0; i < 4; i++) {
            int idx = tid + i * 256;
            fdst[idx] = (idx < max4) ? fsrc[idx] : make_float4(0.f, 0.f, 0.f, 0.f);
        }
    }
    __syncthreads();

    int c = tid & 127;
    int g = tid >> 7; // 0 or 1 -> nodes g*8 .. g*8+7
    float accm[8], accv[8];
#pragma unroll
    for (int i = 0; i < 8; i++) { accm[i] = 0.f; accv[i] = 0.f; }

    for (int k4 = 0; k4 < INF / 4; k4++) {
        int k = k4 * 4;
        float wm0 = Wm[(k + 0) * OUTF + c];
        float wm1 = Wm[(k + 1) * OUTF + c];
        float wm2 = Wm[(k + 2) * OUTF + c];
        float wm3 = Wm[(k + 3) * OUTF + c];
        float wv0 = Wv[(k + 0) * OUTF + c];
        float wv1 = Wv[(k + 1) * OUTF + c];
        float wv2 = Wv[(k + 2) * OUTF + c];
        float wv3 = Wv[(k + 3) * OUTF + c];
#pragma unroll
        for (int i = 0; i < 8; i++) {
            float4 f = *(const float4*)&feat_s[g * 8 + i][k];
            accm[i] += f.x * wm0 + f.y * wm1 + f.z * wm2 + f.w * wm3;
            accv[i] += f.x * wv0 + f.y * wv1 + f.z * wv2 + f.w * wv3;
        }
    }

#pragma unroll
    for (int i = 0; i < 8; i++) {
        int node = node0 + g * 8 + i;
        if (node < n_nodes) {
            float mean = fmaxf(accm[i], 0.f);
            float var = fmaxf(accv[i], 0.f);
            float att = __expf(-var); // GAMMA = 1
            float n1 = norm1[node];
            float n2 = norm2[node];
            m_msg[(size_t)node * OUTF + c] = mean * att * n1;
            v_msg[(size_t)node * OUTF + c] = var * att * att * n2;
        }
    }
}

// ---------------- per-dst aggregation (atomic-free) + final norm ----------------
__global__ __launch_bounds__(128) void agg_kernel(const int* __restrict__ row_start,
                                                  const int* __restrict__ srcs,
                                                  const float* __restrict__ m_msg,
                                                  const float* __restrict__ v_msg,
                                                  const float* __restrict__ norm1,
                                                  const float* __restrict__ norm2,
                                                  float* __restrict__ out_mean,
                                                  float* __restrict__ out_var) {
    int d = blockIdx.x;
    int t = threadIdx.x;
    int s0 = row_start[d];
    int s1 = row_start[d + 1];
    float am = 0.f, av = 0.f;
    int i = s0;
    for (; i + 1 < s1; i += 2) {
        int sa = srcs[i];
        int sb = srcs[i + 1];
        float ma = m_msg[(size_t)sa * OUTF + t];
        float mb = m_msg[(size_t)sb * OUTF + t];
        float va = v_msg[(size_t)sa * OUTF + t];
        float vb = v_msg[(size_t)sb * OUTF + t];
        am += ma + mb;
        av += va + vb;
    }
    if (i < s1) {
        int sa = srcs[i];
        am += m_msg[(size_t)sa * OUTF + t];
        av += v_msg[(size_t)sa * OUTF + t];
    }
    out_mean[(size_t)d * OUTF + t] = am * norm1[d];
    out_var[(size_t)d * OUTF + t] = av * norm2[d];
}

extern "C" void kernel_launch(void* const* d_in, const int* in_sizes, int n_in,
                              void* d_out, int out_size, void* d_ws, size_t ws_size,
                              hipStream_t stream) {
    const float* feat = (const float*)d_in[0];
    const float* Wm = (const float*)d_in[1];
    const float* Wv = (const float*)d_in[2];
    const int* src = (const int*)d_in[3];
    const int* dst = (const int*)d_in[4];
    float* out = (float*)d_out;

    const int N = N_NODES;
    const int E = N_EDGES;

    // carve workspace (256B aligned)
    char* w = (char*)d_ws;
    auto carve = [&](size_t bytes) {
        char* p = w;
        w += (bytes + 255) & ~(size_t)255;
        return p;
    };
    float* m_msg = (float*)carve((size_t)N * OUTF * 4);
    float* v_msg = (float*)carve((size_t)N * OUTF * 4);
    int* srcs_sorted = (int*)carve((size_t)E * 4);
    int* deg = (int*)carve((size_t)N * 4);
    int* row_start = (int*)carve((size_t)(N + 1) * 4);
    int* cursor = (int*)carve((size_t)N * 4);
    float* norm1 = (float*)carve((size_t)N * 4);
    float* norm2 = (float*)carve((size_t)N * 4);
    int* partial = (int*)carve(128 * 4);

    hipMemsetAsync(deg, 0, (size_t)N * 4, stream);

    count_deg_kernel<<<(E + 255) / 256, 256, 0, stream>>>(dst, E, deg);
    scan_partial_kernel<<<SCAN_BLOCKS, 256, 0, stream>>>(deg, N, partial);
    scan_top_kernel<<<1, 128, 0, stream>>>(partial, SCAN_BLOCKS, row_start, N);
    scan_final_kernel<<<SCAN_BLOCKS, 256, 0, stream>>>(deg, N, partial, row_start, cursor,
                                                       norm1, norm2);
    scatter_edges_kernel<<<(E + 255) / 256, 256, 0, stream>>>(src, dst, E, cursor, srcs_sorted);
    proj_kernel<<<(N + NODE_TILE - 1) / NODE_TILE, 256, 0, stream>>>(feat, Wm, Wv, norm1, norm2,
                                                                     m_msg, v_msg, N);
    agg_kernel<<<N, 128, 0, stream>>>(row_start, srcs_sorted, m_msg, v_msg, norm1, norm2,
                                      out, out + (size_t)N * OUTF);
}

// Round 2
// 571.689 us; speedup vs baseline: 1.5093x; 1.5093x over previous
//
#include <hip/hip_runtime.h>
#include <hip/hip_bf16.h>

#define N_NODES 100000
#define N_EDGES 1600000
#define OUTF 128
#define INF 256
#define SCAN_CHUNK 1024
#define SCAN_BLOCKS 98   // 98*1024 = 100352 >= 100000
#define M_TILES 6250     // 100000 / 16

typedef _Float16 f16;
typedef _Float16 half8 __attribute__((ext_vector_type(8)));
typedef _Float16 half2v __attribute__((ext_vector_type(2)));
typedef float floatx4 __attribute__((ext_vector_type(4)));

// ---------------- degree count ----------------
__global__ void count_deg_kernel(const int* __restrict__ dst, int E, int* __restrict__ deg) {
    int i = blockIdx.x * blockDim.x + threadIdx.x;
    if (i < E) atomicAdd(&deg[dst[i]], 1);
}

// ---------------- scan step 1: per-chunk sums ----------------
__global__ __launch_bounds__(256) void scan_partial_kernel(const int* __restrict__ deg, int n,
                                                           int* __restrict__ partial) {
    __shared__ int red[256];
    int b = blockIdx.x, t = threadIdx.x;
    int base = b * SCAN_CHUNK;
    int s = 0;
    for (int i = t; i < SCAN_CHUNK; i += 256) {
        int idx = base + i;
        if (idx < n) s += deg[idx];
    }
    red[t] = s;
    __syncthreads();
    for (int off = 128; off > 0; off >>= 1) {
        if (t < off) red[t] += red[t + off];
        __syncthreads();
    }
    if (t == 0) partial[b] = red[0];
}

// ---------------- scan step 2: exclusive scan of partials (nb <= 128) ----------------
__global__ __launch_bounds__(128) void scan_top_kernel(int* __restrict__ partial, int nb,
                                                       int* __restrict__ row_start, int n) {
    __shared__ int sc[128];
    int t = threadIdx.x;
    int v = (t < nb) ? partial[t] : 0;
    sc[t] = v;
    __syncthreads();
    for (int off = 1; off < 128; off <<= 1) {
        int val = sc[t];
        int add = (t >= off) ? sc[t - off] : 0;
        __syncthreads();
        sc[t] = val + add;
        __syncthreads();
    }
    if (t < nb) partial[t] = sc[t] - v;   // exclusive
    if (t == 127) row_start[n] = sc[127]; // total edge count
}

// ---------------- scan step 3: per-chunk exclusive scan + norms ----------------
__global__ __launch_bounds__(256) void scan_final_kernel(const int* __restrict__ deg, int n,
                                                         const int* __restrict__ partial,
                                                         int* __restrict__ row_start,
                                                         int* __restrict__ cursor,
                                                         float* __restrict__ norm1,
                                                         float* __restrict__ norm2) {
    __shared__ int sc[256];
    int b = blockIdx.x, t = threadIdx.x;
    int base = b * SCAN_CHUNK + t * 4;
    int v[4];
    int tsum = 0;
#pragma unroll
    for (int j = 0; j < 4; j++) {
        int idx = base + j;
        v[j] = (idx < n) ? deg[idx] : 0;
        tsum += v[j];
    }
    sc[t] = tsum;
    __syncthreads();
    for (int off = 1; off < 256; off <<= 1) {
        int val = sc[t];
        int add = (t >= off) ? sc[t - off] : 0;
        __syncthreads();
        sc[t] = val + add;
        __syncthreads();
    }
    int run = sc[t] - tsum + partial[b];
#pragma unroll
    for (int j = 0; j < 4; j++) {
        int idx = base + j;
        if (idx < n) {
            row_start[idx] = run;
            cursor[idx] = run;
            float d = (float)(v[j] > 0 ? v[j] : 1); // clip(deg, 1)
            norm1[idx] = rsqrtf(d);
            norm2[idx] = 1.0f / d;
            run += v[j];
        }
    }
}

// ---------------- edge scatter into CSR slots ----------------
__global__ void scatter_edges_kernel(const int* __restrict__ src, const int* __restrict__ dst,
                                     int E, int* __restrict__ cursor, int* __restrict__ srcs_sorted) {
    int i = blockIdx.x * blockDim.x + threadIdx.x;
    if (i < E) {
        int d = dst[i];
        int p = atomicAdd(&cursor[d], 1);
        srcs_sorted[p] = src[i];
    }
}

// ---------------- convert W_mean|W_var into f16 Bt, wave-friendly layout ----------------
// Bt row ng = g*16 + i, g = w*4 + cg; cg 0/1 -> mean cols, cg 2/3 -> var cols
// actual col = w*32 + (cg&1)*16 + i;  Bt[ng][k] = W[k][col]
__global__ __launch_bounds__(256) void convert_B_kernel(const float* __restrict__ Wm,
                                                        const float* __restrict__ Wv,
                                                        f16* __restrict__ Bt) {
    int k = threadIdx.x;
    int ng = blockIdx.x;
    int g = ng >> 4, i = ng & 15;
    int w = g >> 2, cg = g & 3;
    int col = w * 32 + (cg & 1) * 16 + i;
    const float* srcW = (cg >= 2) ? Wv : Wm;
    Bt[ng * 256 + k] = (f16)srcW[k * 128 + col];
}

// ---------------- MFMA projection + relu + attention + msg (f16, interleaved) -------
// block = 256 (4 waves). Wave w owns output cols [w*32, w*32+32) for BOTH mean & var.
// B frags held in registers (128 VGPR); A frags loaded straight from global. No LDS.
__global__ __launch_bounds__(256, 2) void proj_mfma_kernel(const float* __restrict__ feat,
                                                           const f16* __restrict__ Bt,
                                                           const float* __restrict__ norm1,
                                                           const float* __restrict__ norm2,
                                                           f16* __restrict__ msg) {
    int tid = threadIdx.x;
    int w = tid >> 6;
    int lane = tid & 63;
    int quad = lane >> 4;
    int l15 = lane & 15;

    // load B fragments once: 4 col-groups x 8 k-frags
    half8 b[4][8];
#pragma unroll
    for (int cg = 0; cg < 4; cg++) {
        int g = w * 4 + cg;
        const f16* bp = Bt + (size_t)(g * 16 + l15) * 256 + quad * 8;
#pragma unroll
        for (int kf = 0; kf < 8; kf++) {
            b[cg][kf] = *(const half8*)(bp + kf * 32);
        }
    }

    for (int t = blockIdx.x; t < M_TILES; t += gridDim.x) {
        int m0 = t * 16;
        // A fragments: 8 consecutive fp32 per lane per frag -> cvt to f16
        half8 a[8];
        const float* ap = feat + (size_t)(m0 + l15) * 256 + quad * 8;
#pragma unroll
        for (int kf = 0; kf < 8; kf++) {
            floatx4 f0 = *(const floatx4*)(ap + kf * 32);
            floatx4 f1 = *(const floatx4*)(ap + kf * 32 + 4);
            half8 h;
            h[0] = (f16)f0.x; h[1] = (f16)f0.y; h[2] = (f16)f0.z; h[3] = (f16)f0.w;
            h[4] = (f16)f1.x; h[5] = (f16)f1.y; h[6] = (f16)f1.z; h[7] = (f16)f1.w;
            a[kf] = h;
        }

        floatx4 acc[4];
#pragma unroll
        for (int cg = 0; cg < 4; cg++) acc[cg] = (floatx4){0.f, 0.f, 0.f, 0.f};

#pragma unroll
        for (int cg = 0; cg < 4; cg++) {
#pragma unroll
            for (int kf = 0; kf < 8; kf++) {
                acc[cg] = __builtin_amdgcn_mfma_f32_16x16x32_f16(a[kf], b[cg][kf], acc[cg], 0, 0, 0);
            }
        }

        // epilogue: cg 0/1 = mean, cg 2/3 = var (same cols)
#pragma unroll
        for (int cg = 0; cg < 2; cg++) {
            int col = w * 32 + cg * 16 + l15;
#pragma unroll
            for (int r = 0; r < 4; r++) {
                int row = quad * 4 + r;
                int node = m0 + row;
                float m = fmaxf(acc[cg][r], 0.f);
                float v = fmaxf(acc[cg + 2][r], 0.f);
                float att = __expf(-v); // GAMMA = 1
                float s1 = norm1[node];
                float s2 = norm2[node];
                msg[(size_t)node * 256 + col] = (f16)(m * att * s1);
                msg[(size_t)node * 256 + 128 + col] = (f16)(v * att * att * s2);
            }
        }
    }
}

// ---------------- per-dst aggregation (wave per dst) + final norm ----------------
// msg row: [m0..m127 | v0..v127] f16 (512 B). lane handles cols 2*lane, 2*lane+1.
__global__ __launch_bounds__(256) void agg_kernel(const int* __restrict__ row_start,
                                                  const int* __restrict__ srcs,
                                                  const f16* __restrict__ msg,
                                                  const float* __restrict__ norm1,
                                                  const float* __restrict__ norm2,
                                                  float* __restrict__ out_mean,
                                                  float* __restrict__ out_var) {
    int d = blockIdx.x * 4 + (threadIdx.x >> 6);
    int lane = threadIdx.x & 63;
    int s0 = row_start[d];
    int s1 = row_start[d + 1];
    float am0 = 0.f, am1 = 0.f, av0 = 0.f, av1 = 0.f;
    int i = s0;
    for (; i + 3 < s1; i += 4) {
        int sa = srcs[i], sb = srcs[i + 1], sc = srcs[i + 2], sd = srcs[i + 3];
        half2v ma = *(const half2v*)(msg + (size_t)sa * 256 + lane * 2);
        half2v va = *(const half2v*)(msg + (size_t)sa * 256 + 128 + lane * 2);
        half2v mb = *(const half2v*)(msg + (size_t)sb * 256 + lane * 2);
        half2v vb = *(const half2v*)(msg + (size_t)sb * 256 + 128 + lane * 2);
        half2v mc = *(const half2v*)(msg + (size_t)sc * 256 + lane * 2);
        half2v vc = *(const half2v*)(msg + (size_t)sc * 256 + 128 + lane * 2);
        half2v md = *(const half2v*)(msg + (size_t)sd * 256 + lane * 2);
        half2v vd = *(const half2v*)(msg + (size_t)sd * 256 + 128 + lane * 2);
        am0 += (float)ma[0] + (float)mb[0] + (float)mc[0] + (float)md[0];
        am1 += (float)ma[1] + (float)mb[1] + (float)mc[1] + (float)md[1];
        av0 += (float)va[0] + (float)vb[0] + (float)vc[0] + (float)vd[0];
        av1 += (float)va[1] + (float)vb[1] + (float)vc[1] + (float)vd[1];
    }
    for (; i < s1; i++) {
        int sa = srcs[i];
        half2v ma = *(const half2v*)(msg + (size_t)sa * 256 + lane * 2);
        half2v va = *(const half2v*)(msg + (size_t)sa * 256 + 128 + lane * 2);
        am0 += (float)ma[0];
        am1 += (float)ma[1];
        av0 += (float)va[0];
        av1 += (float)va[1];
    }
    float k1 = norm1[d], k2 = norm2[d];
    float2 om = make_float2(am0 * k1, am1 * k1);
    float2 ov = make_float2(av0 * k2, av1 * k2);
    *(float2*)(out_mean + (size_t)d * 128 + lane * 2) = om;
    *(float2*)(out_var + (size_t)d * 128 + lane * 2) = ov;
}

extern "C" void kernel_launch(void* const* d_in, const int* in_sizes, int n_in,
                              void* d_out, int out_size, void* d_ws, size_t ws_size,
                              hipStream_t stream) {
    const float* feat = (const float*)d_in[0];
    const float* Wm = (const float*)d_in[1];
    const float* Wv = (const float*)d_in[2];
    const int* src = (const int*)d_in[3];
    const int* dst = (const int*)d_in[4];
    float* out = (float*)d_out;

    const int N = N_NODES;
    const int E = N_EDGES;

    char* wsp = (char*)d_ws;
    auto carve = [&](size_t bytes) {
        char* p = wsp;
        wsp += (bytes + 255) & ~(size_t)255;
        return p;
    };
    f16* msg = (f16*)carve((size_t)N * 256 * sizeof(f16));   // [m|v] interleaved, 51.2 MB
    f16* Bt = (f16*)carve((size_t)256 * 256 * sizeof(f16));  // 128 KB
    int* srcs_sorted = (int*)carve((size_t)E * 4);
    int* deg = (int*)carve((size_t)N * 4);
    int* row_start = (int*)carve((size_t)(N + 1) * 4);
    int* cursor = (int*)carve((size_t)N * 4);
    float* norm1 = (float*)carve((size_t)N * 4);
    float* norm2 = (float*)carve((size_t)N * 4);
    int* partial = (int*)carve(128 * 4);

    hipMemsetAsync(deg, 0, (size_t)N * 4, stream);

    count_deg_kernel<<<(E + 255) / 256, 256, 0, stream>>>(dst, E, deg);
    convert_B_kernel<<<256, 256, 0, stream>>>(Wm, Wv, Bt);
    scan_partial_kernel<<<SCAN_BLOCKS, 256, 0, stream>>>(deg, N, partial);
    scan_top_kernel<<<1, 128, 0, stream>>>(partial, SCAN_BLOCKS, row_start, N);
    scan_final_kernel<<<SCAN_BLOCKS, 256, 0, stream>>>(deg, N, partial, row_start, cursor,
                                                       norm1, norm2);
    scatter_edges_kernel<<<(E + 255) / 256, 256, 0, stream>>>(src, dst, E, cursor, srcs_sorted);
    proj_mfma_kernel<<<1250, 256, 0, stream>>>(feat, Bt, norm1, norm2, msg);
    agg_kernel<<<N / 4, 256, 0, stream>>>(row_start, srcs_sorted, msg, norm1, norm2,
                                          out, out + (size_t)N * OUTF);
}

// Round 3
// 493.426 us; speedup vs baseline: 1.7487x; 1.1586x over previous
//
#include <hip/hip_runtime.h>
#include <hip/hip_bf16.h>

#define N_NODES 100000
#define N_EDGES 1600000
#define OUTF 128
#define INF 256
#define SCAN_CHUNK 1024
#define SCAN_BLOCKS 98   // 98*1024 = 100352 >= 100000
#define M_TILES 6250     // 100000 / 16

typedef _Float16 f16;
typedef _Float16 half8 __attribute__((ext_vector_type(8)));
typedef _Float16 half2v __attribute__((ext_vector_type(2)));
typedef float floatx4 __attribute__((ext_vector_type(4)));

// ---------------- fused degree count + edge rank (ONE atomic pass) ----------------
__global__ void count_rank_kernel(const int* __restrict__ dst, int E,
                                  int* __restrict__ deg, int* __restrict__ rank) {
    int i = blockIdx.x * blockDim.x + threadIdx.x;
    if (i < E) rank[i] = atomicAdd(&deg[dst[i]], 1);
}

// ---------------- scan step 1: per-chunk sums ----------------
__global__ __launch_bounds__(256) void scan_partial_kernel(const int* __restrict__ deg, int n,
                                                           int* __restrict__ partial) {
    __shared__ int red[256];
    int b = blockIdx.x, t = threadIdx.x;
    int base = b * SCAN_CHUNK;
    int s = 0;
    for (int i = t; i < SCAN_CHUNK; i += 256) {
        int idx = base + i;
        if (idx < n) s += deg[idx];
    }
    red[t] = s;
    __syncthreads();
    for (int off = 128; off > 0; off >>= 1) {
        if (t < off) red[t] += red[t + off];
        __syncthreads();
    }
    if (t == 0) partial[b] = red[0];
}

// ---------------- scan step 2: exclusive scan of partials (nb <= 128) ----------------
__global__ __launch_bounds__(128) void scan_top_kernel(int* __restrict__ partial, int nb,
                                                       int* __restrict__ row_start, int n) {
    __shared__ int sc[128];
    int t = threadIdx.x;
    int v = (t < nb) ? partial[t] : 0;
    sc[t] = v;
    __syncthreads();
    for (int off = 1; off < 128; off <<= 1) {
        int val = sc[t];
        int add = (t >= off) ? sc[t - off] : 0;
        __syncthreads();
        sc[t] = val + add;
        __syncthreads();
    }
    if (t < nb) partial[t] = sc[t] - v;   // exclusive
    if (t == 127) row_start[n] = sc[127]; // total edge count
}

// ---------------- scan step 3: per-chunk exclusive scan + norms ----------------
__global__ __launch_bounds__(256) void scan_final_kernel(const int* __restrict__ deg, int n,
                                                         const int* __restrict__ partial,
                                                         int* __restrict__ row_start,
                                                         float* __restrict__ norm1,
                                                         float* __restrict__ norm2) {
    __shared__ int sc[256];
    int b = blockIdx.x, t = threadIdx.x;
    int base = b * SCAN_CHUNK + t * 4;
    int v[4];
    int tsum = 0;
#pragma unroll
    for (int j = 0; j < 4; j++) {
        int idx = base + j;
        v[j] = (idx < n) ? deg[idx] : 0;
        tsum += v[j];
    }
    sc[t] = tsum;
    __syncthreads();
    for (int off = 1; off < 256; off <<= 1) {
        int val = sc[t];
        int add = (t >= off) ? sc[t - off] : 0;
        __syncthreads();
        sc[t] = val + add;
        __syncthreads();
    }
    int run = sc[t] - tsum + partial[b];
#pragma unroll
    for (int j = 0; j < 4; j++) {
        int idx = base + j;
        if (idx < n) {
            row_start[idx] = run;
            float d = (float)(v[j] > 0 ? v[j] : 1); // clip(deg, 1)
            norm1[idx] = rsqrtf(d);
            norm2[idx] = 1.0f / d;
            run += v[j];
        }
    }
}

// ---------------- edge scatter into CSR slots (atomic-free) ----------------
__global__ void scatter_edges_kernel(const int* __restrict__ src, const int* __restrict__ dst,
                                     const int* __restrict__ rank,
                                     const int* __restrict__ row_start,
                                     int E, int* __restrict__ srcs_sorted) {
    int i = blockIdx.x * blockDim.x + threadIdx.x;
    if (i < E) {
        srcs_sorted[row_start[dst[i]] + rank[i]] = src[i];
    }
}

// ---------------- convert W_mean|W_var into f16 Bt, wave-friendly layout ----------------
// Bt row ng = g*16 + i, g = w*4 + cg; cg 0/1 -> mean cols, cg 2/3 -> var cols
// actual col = w*32 + (cg&1)*16 + i;  Bt[ng][k] = W[k][col]
__global__ __launch_bounds__(256) void convert_B_kernel(const float* __restrict__ Wm,
                                                        const float* __restrict__ Wv,
                                                        f16* __restrict__ Bt) {
    int k = threadIdx.x;
    int ng = blockIdx.x;
    int g = ng >> 4, i = ng & 15;
    int w = g >> 2, cg = g & 3;
    int col = w * 32 + (cg & 1) * 16 + i;
    const float* srcW = (cg >= 2) ? Wv : Wm;
    Bt[ng * 256 + k] = (f16)srcW[k * 128 + col];
}

// ---------------- MFMA projection + relu + attention + msg (f16, interleaved) -------
// block = 256 (4 waves). Wave w owns output cols [w*32, w*32+32) for BOTH mean & var.
// B frags held in registers; A frags loaded straight from global. No LDS.
__global__ __launch_bounds__(256, 2) void proj_mfma_kernel(const float* __restrict__ feat,
                                                           const f16* __restrict__ Bt,
                                                           const float* __restrict__ norm1,
                                                           const float* __restrict__ norm2,
                                                           f16* __restrict__ msg) {
    int tid = threadIdx.x;
    int w = tid >> 6;
    int lane = tid & 63;
    int quad = lane >> 4;
    int l15 = lane & 15;

    // load B fragments once: 4 col-groups x 8 k-frags
    half8 b[4][8];
#pragma unroll
    for (int cg = 0; cg < 4; cg++) {
        int g = w * 4 + cg;
        const f16* bp = Bt + (size_t)(g * 16 + l15) * 256 + quad * 8;
#pragma unroll
        for (int kf = 0; kf < 8; kf++) {
            b[cg][kf] = *(const half8*)(bp + kf * 32);
        }
    }

    for (int t = blockIdx.x; t < M_TILES; t += gridDim.x) {
        int m0 = t * 16;
        half8 a[8];
        const float* ap = feat + (size_t)(m0 + l15) * 256 + quad * 8;
#pragma unroll
        for (int kf = 0; kf < 8; kf++) {
            floatx4 f0 = *(const floatx4*)(ap + kf * 32);
            floatx4 f1 = *(const floatx4*)(ap + kf * 32 + 4);
            half8 h;
            h[0] = (f16)f0.x; h[1] = (f16)f0.y; h[2] = (f16)f0.z; h[3] = (f16)f0.w;
            h[4] = (f16)f1.x; h[5] = (f16)f1.y; h[6] = (f16)f1.z; h[7] = (f16)f1.w;
            a[kf] = h;
        }

        floatx4 acc[4];
#pragma unroll
        for (int cg = 0; cg < 4; cg++) acc[cg] = (floatx4){0.f, 0.f, 0.f, 0.f};

#pragma unroll
        for (int cg = 0; cg < 4; cg++) {
#pragma unroll
            for (int kf = 0; kf < 8; kf++) {
                acc[cg] = __builtin_amdgcn_mfma_f32_16x16x32_f16(a[kf], b[cg][kf], acc[cg], 0, 0, 0);
            }
        }

        // epilogue: cg 0/1 = mean, cg 2/3 = var (same cols)
#pragma unroll
        for (int cg = 0; cg < 2; cg++) {
            int col = w * 32 + cg * 16 + l15;
#pragma unroll
            for (int r = 0; r < 4; r++) {
                int row = quad * 4 + r;
                int node = m0 + row;
                float m = fmaxf(acc[cg][r], 0.f);
                float v = fmaxf(acc[cg + 2][r], 0.f);
                float att = __expf(-v); // GAMMA = 1
                float s1 = norm1[node];
                float s2 = norm2[node];
                msg[(size_t)node * 256 + col] = (f16)(m * att * s1);
                msg[(size_t)node * 256 + 128 + col] = (f16)(v * att * att * s2);
            }
        }
    }
}

// ---------------- per-dst aggregation (wave per dst) + final norm ----------------
// msg row: [m0..m127 | v0..v127] f16 (512 B). lane handles cols 2*lane, 2*lane+1.
__global__ __launch_bounds__(256) void agg_kernel(const int* __restrict__ row_start,
                                                  const int* __restrict__ srcs,
                                                  const f16* __restrict__ msg,
                                                  const float* __restrict__ norm1,
                                                  const float* __restrict__ norm2,
                                                  float* __restrict__ out_mean,
                                                  float* __restrict__ out_var) {
    int d = blockIdx.x * 4 + (threadIdx.x >> 6);
    int lane = threadIdx.x & 63;
    int s0 = row_start[d];
    int s1 = row_start[d + 1];
    float am0 = 0.f, am1 = 0.f, av0 = 0.f, av1 = 0.f;
    int i = s0;
    for (; i + 3 < s1; i += 4) {
        int sa = srcs[i], sb = srcs[i + 1], sc = srcs[i + 2], sd = srcs[i + 3];
        half2v ma = *(const half2v*)(msg + (size_t)sa * 256 + lane * 2);
        half2v va = *(const half2v*)(msg + (size_t)sa * 256 + 128 + lane * 2);
        half2v mb = *(const half2v*)(msg + (size_t)sb * 256 + lane * 2);
        half2v vb = *(const half2v*)(msg + (size_t)sb * 256 + 128 + lane * 2);
        half2v mc = *(const half2v*)(msg + (size_t)sc * 256 + lane * 2);
        half2v vc = *(const half2v*)(msg + (size_t)sc * 256 + 128 + lane * 2);
        half2v md = *(const half2v*)(msg + (size_t)sd * 256 + lane * 2);
        half2v vd = *(const half2v*)(msg + (size_t)sd * 256 + 128 + lane * 2);
        am0 += (float)ma[0] + (float)mb[0] + (float)mc[0] + (float)md[0];
        am1 += (float)ma[1] + (float)mb[1] + (float)mc[1] + (float)md[1];
        av0 += (float)va[0] + (float)vb[0] + (float)vc[0] + (float)vd[0];
        av1 += (float)va[1] + (float)vb[1] + (float)vc[1] + (float)vd[1];
    }
    for (; i < s1; i++) {
        int sa = srcs[i];
        half2v ma = *(const half2v*)(msg + (size_t)sa * 256 + lane * 2);
        half2v va = *(const half2v*)(msg + (size_t)sa * 256 + 128 + lane * 2);
        am0 += (float)ma[0];
        am1 += (float)ma[1];
        av0 += (float)va[0];
        av1 += (float)va[1];
    }
    float k1 = norm1[d], k2 = norm2[d];
    float2 om = make_float2(am0 * k1, am1 * k1);
    float2 ov = make_float2(av0 * k2, av1 * k2);
    *(float2*)(out_mean + (size_t)d * 128 + lane * 2) = om;
    *(float2*)(out_var + (size_t)d * 128 + lane * 2) = ov;
}

extern "C" void kernel_launch(void* const* d_in, const int* in_sizes, int n_in,
                              void* d_out, int out_size, void* d_ws, size_t ws_size,
                              hipStream_t stream) {
    const float* feat = (const float*)d_in[0];
    const float* Wm = (const float*)d_in[1];
    const float* Wv = (const float*)d_in[2];
    const int* src = (const int*)d_in[3];
    const int* dst = (const int*)d_in[4];
    float* out = (float*)d_out;

    const int N = N_NODES;
    const int E = N_EDGES;

    char* wsp = (char*)d_ws;
    auto carve = [&](size_t bytes) {
        char* p = wsp;
        wsp += (bytes + 255) & ~(size_t)255;
        return p;
    };
    f16* msg = (f16*)carve((size_t)N * 256 * sizeof(f16));   // [m|v] interleaved, 51.2 MB
    f16* Bt = (f16*)carve((size_t)256 * 256 * sizeof(f16));  // 128 KB
    int* srcs_sorted = (int*)carve((size_t)E * 4);
    int* rank = (int*)carve((size_t)E * 4);
    int* deg = (int*)carve((size_t)N * 4);
    int* row_start = (int*)carve((size_t)(N + 1) * 4);
    float* norm1 = (float*)carve((size_t)N * 4);
    float* norm2 = (float*)carve((size_t)N * 4);
    int* partial = (int*)carve(128 * 4);

    hipMemsetAsync(deg, 0, (size_t)N * 4, stream);

    count_rank_kernel<<<(E + 255) / 256, 256, 0, stream>>>(dst, E, deg, rank);
    convert_B_kernel<<<256, 256, 0, stream>>>(Wm, Wv, Bt);
    scan_partial_kernel<<<SCAN_BLOCKS, 256, 0, stream>>>(deg, N, partial);
    scan_top_kernel<<<1, 128, 0, stream>>>(partial, SCAN_BLOCKS, row_start, N);
    scan_final_kernel<<<SCAN_BLOCKS, 256, 0, stream>>>(deg, N, partial, row_start, norm1, norm2);
    scatter_edges_kernel<<<(E + 255) / 256, 256, 0, stream>>>(src, dst, rank, row_start, E,
                                                              srcs_sorted);
    proj_mfma_kernel<<<1250, 256, 0, stream>>>(feat, Bt, norm1, norm2, msg);
    agg_kernel<<<N / 4, 256, 0, stream>>>(row_start, srcs_sorted, msg, norm1, norm2,
                                          out, out + (size_t)N * OUTF);
}